// Round 18
// baseline (166.247 us; speedup 1.0000x reference)
//
#include <hip/hip_runtime.h>

typedef __attribute__((ext_vector_type(8))) short short8;   // 8 bf16 (4 VGPR)
typedef __attribute__((ext_vector_type(4))) float f32x4;    // MFMA C/D
typedef __attribute__((ext_vector_type(4))) int int4v;

#define CHUNK 1024
#define NBINS 32
#define NCLS  10
#define NREP  8

__global__ __launch_bounds__(256) void dvh_main(
    const float* __restrict__ pred, const float* __restrict__ targ,
    const float* __restrict__ mask, float* __restrict__ gD, float* __restrict__ gN,
    int* __restrict__ ticket, float* __restrict__ out,
    int chunksPerN, int chunksTotal)
{
    __shared__ float2 sE[CHUNK];                 // (Ep,Et) per voxel, 8 KB
    __shared__ unsigned short mT[NCLS * CHUNK];  // bf16 masks [10][1024] swizzled, 20 KB

    const int tid  = threadIdx.x;
    const int lane = tid & 63;
    const int w    = tid >> 6;       // wave 0..3
    const int n15  = lane & 15;      // MFMA row/col index
    const int g    = lane >> 4;      // k-group 0..3

    const int chunk = blockIdx.x;
    const size_t vbase = (size_t)chunk * CHUNK;

    // ---- issue ALL global loads first (latency overlaps across blocks) ----
    float4 p = ((const float4*)(pred + vbase))[tid];     // voxels 4t..4t+3
    float4 t = ((const float4*)(targ + vbase))[tid];
    uint4 mv[10];
    {
        const uint4* m4g = (const uint4*)(mask + vbase * NCLS);
        #pragma unroll
        for (int k = 0; k < 10; ++k) mv[k] = m4g[k * 256 + tid];
    }

    const float K1 = __expf((float)n15);        // e^bin, bins 0..15
    const float K2 = K1 * 8886110.5f;           // * e^16 -> bins 16..31

    // ---- stage doses: exp once per voxel ----
    *(float4*)&sE[4 * tid]     = make_float4(__expf(-32.f * p.x), __expf(-32.f * t.x),
                                             __expf(-32.f * p.y), __expf(-32.f * t.y));
    *(float4*)&sE[4 * tid + 2] = make_float4(__expf(-32.f * p.z), __expf(-32.f * t.z),
                                             __expf(-32.f * p.w), __expf(-32.f * t.w));
    // ---- stage masks: 0/1 f32 -> bf16 (top 16 bits), swizzled transpose ----
    {
        int f0 = tid * 4;
        int vv = f0 / 10;
        int cc = f0 - vv * 10;
        #pragma unroll
        for (int k = 0; k < 10; ++k) {
            unsigned int e[4] = {mv[k].x, mv[k].y, mv[k].z, mv[k].w};
            #pragma unroll
            for (int q = 0; q < 4; ++q) {
                mT[cc * CHUNK + (((vv >> 3) ^ (cc & 7)) << 3) + (vv & 7)] =
                    (unsigned short)(e[q] >> 16);
                cc += 1;
                int wrap = (cc >= 10);
                cc -= wrap * 10;
                vv += wrap;
            }
            vv += 102;   // k-stride 1024 floats = 102*10 + 4
        }
    }
    __syncthreads();

    f32x4 acc1 = {0,0,0,0};          // bins 0-15
    f32x4 acc2 = {0,0,0,0};          // bins 16-31
    f32x4 cnt  = {0,0,0,0};          // voxel counts
    short8 ones;
    #pragma unroll
    for (int i = 0; i < 8; ++i) ones[i] = (short)0x3F80;   // bf16 1.0

    // B-row: lanes n15>=10 have no class; read row n15-10 (junk-but-valid,
    // feeds only MFMA output columns 10..15, which are never consumed).
    const int brow = (n15 < NCLS) ? n15 : (n15 - NCLS);

    #pragma unroll
    for (int st = 0; st < 8; ++st) {
        const int vb = (w * 8 + st) * 32;    // this wave's 32-voxel K-block
        const int v0 = vb + g * 8;           // this lane's 8 voxels
        short8 fb = *(const short8*)&mT[brow * CHUNK + (((v0 >> 3) ^ (brow & 7)) << 3)];
        const float4* e4 = (const float4*)&sE[v0];

        int u1[4], u2[4];
        #pragma unroll
        for (int j = 0; j < 4; ++j) {
            float4 q = e4[j];                 // vox a: (q.x,q.y)  vox b: (q.z,q.w)
            float dea = q.y - q.x, deb = q.w - q.z;
            float pa = fmaf(q.x, K1, 1.f) * fmaf(q.y, K1, 1.f);
            float pb = fmaf(q.z, K1, 1.f) * fmaf(q.w, K1, 1.f);
            float sa = dea * K1 * __builtin_amdgcn_rcpf(pa);
            float sb = deb * K1 * __builtin_amdgcn_rcpf(pb);
            unsigned h1;
            asm("v_cvt_pk_bf16_f32 %0, %1, %2" : "=v"(h1) : "v"(sa), "v"(sb));
            u1[j] = (int)h1;
            float pc = fmaf(q.x, K2, 1.f) * fmaf(q.y, K2, 1.f);
            float pd = fmaf(q.z, K2, 1.f) * fmaf(q.w, K2, 1.f);
            float sc = dea * K2 * __builtin_amdgcn_rcpf(pc);
            float sd = deb * K2 * __builtin_amdgcn_rcpf(pd);
            unsigned h2;
            asm("v_cvt_pk_bf16_f32 %0, %1, %2" : "=v"(h2) : "v"(sc), "v"(sd));
            u2[j] = (int)h2;
        }
        int4v t1 = {u1[0], u1[1], u1[2], u1[3]};
        int4v t2 = {u2[0], u2[1], u2[2], u2[3]};
        short8 A1 = __builtin_bit_cast(short8, t1);
        short8 A2 = __builtin_bit_cast(short8, t2);

        acc1 = __builtin_amdgcn_mfma_f32_16x16x32_bf16(A1, fb, acc1, 0, 0, 0);
        acc2 = __builtin_amdgcn_mfma_f32_16x16x32_bf16(A2, fb, acc2, 0, 0, 0);
        cnt  = __builtin_amdgcn_mfma_f32_16x16x32_bf16(ones, fb, cnt, 0, 0, 0);
    }
    __syncthreads();                  // all waves done reading mT

    // ---- epilogue: block reduce via LDS (reuse mT), then replicated atomics ----
    float* red  = (float*)mT;        // [4 waves][32 bins][10 cls] = 1280 floats
    float* redN = red + 1280;        // [4 waves][10]

    if (n15 < NCLS) {
        #pragma unroll
        for (int r = 0; r < 4; ++r) {
            int b1 = g * 4 + r;                  // C/D: row=(lane>>4)*4+reg, col=lane&15
            red[(w * 32 + b1) * NCLS + n15]      = acc1[r];
            red[(w * 32 + 16 + b1) * NCLS + n15] = acc2[r];
        }
    }
    if (lane < NCLS) redN[w * NCLS + lane] = cnt[0];   // row 0 of count tile
    __syncthreads();

    const int rep = chunk & (NREP - 1);
    float* gDr = gD + rep * (NBINS * NCLS);
    float* gNr = gN + rep * (2 * NCLS);
    const int nsel = (chunk < chunksPerN) ? 0 : 1;

    for (int i = tid; i < NBINS * NCLS; i += 256) {
        float s = red[i] + red[320 + i] + red[640 + i] + red[960 + i];
        atomicAdd(&gDr[i], s);
    }
    if (tid < NCLS) {
        float s = redN[tid] + redN[10 + tid] + redN[20 + tid] + redN[30 + tid];
        atomicAdd(&gNr[nsel * NCLS + tid], s);
    }

    // ---- fused finalize: last block to finish reduces gD/gN -> out[0] ----
    __shared__ int amLast;
    __syncthreads();                 // drain this block's atomics (vmcnt) first
    if (tid == 0) {
        __threadfence();
        int prev = atomicAdd(ticket, 1);
        amLast = (prev == chunksTotal - 1) ? 1 : 0;
    }
    __syncthreads();
    if (amLast) {
        __shared__ float nvs[2 * NCLS];
        __shared__ float wred[4];
        if (tid < 2 * NCLS) {
            float s = 1.f;
            #pragma unroll
            for (int r = 0; r < NREP; ++r)
                s += __hip_atomic_load(&gN[r * 2 * NCLS + tid],
                                       __ATOMIC_RELAXED, __HIP_MEMORY_SCOPE_AGENT);
            nvs[tid] = s;
        }
        __syncthreads();
        float accv = 0.f;
        #pragma unroll
        for (int ii = 0; ii < 2; ++ii) {
            int i = tid + ii * 256;
            if (i < NBINS * NCLS) {
                float d = 0.f;
                #pragma unroll
                for (int r = 0; r < NREP; ++r)
                    d += __hip_atomic_load(&gD[r * NBINS * NCLS + i],
                                           __ATOMIC_RELAXED, __HIP_MEMORY_SCOPE_AGENT);
                int c = i % NCLS;
                float nv0 = nvs[c], nv1 = nvs[NCLS + c];
                accv += d * d * (1.f / (nv0 * nv0) + 1.f / (nv1 * nv1));
            }
        }
        #pragma unroll
        for (int o = 1; o < 64; o <<= 1) accv += __shfl_xor(accv, o, 64);
        if (lane == 0) wred[w] = accv;
        __syncthreads();
        if (tid == 0)
            out[0] = (wred[0] + wred[1] + wred[2] + wred[3]) * (1.f / 1280.f);
    }
}

extern "C" void kernel_launch(void* const* d_in, const int* in_sizes, int n_in,
                              void* d_out, int out_size, void* d_ws, size_t ws_size,
                              hipStream_t stream) {
    const float* pred = (const float*)d_in[0];
    const float* targ = (const float*)d_in[1];
    const float* mask = (const float*)d_in[2];
    float* gD  = (float*)d_ws;                                       // NREP x 320 floats
    float* gN  = (float*)((char*)d_ws + NREP * NBINS * NCLS * 4);    // NREP x 20 floats
    int* ticket = (int*)((char*)d_ws + NREP * (NBINS * NCLS + 2 * NCLS) * 4);

    hipMemsetAsync(d_ws, 0, NREP * (NBINS * NCLS + 2 * NCLS) * 4 + 4, stream);

    int totalVox    = in_sizes[0];           // N*V = 4194304
    int chunksTotal = totalVox / CHUNK;      // 4096
    int chunksPerN  = chunksTotal / 2;       // 2048

    dvh_main<<<chunksTotal, 256, 0, stream>>>(pred, targ, mask, gD, gN, ticket,
                                              (float*)d_out, chunksPerN, chunksTotal);
}

// Round 19
// 51.273 us; speedup vs baseline: 3.2424x; 3.2424x over previous
//
#include <hip/hip_runtime.h>

typedef __attribute__((ext_vector_type(8))) short short8;   // 8 bf16 (4 VGPR)
typedef __attribute__((ext_vector_type(4))) float f32x4;    // MFMA C/D
typedef __attribute__((ext_vector_type(4))) int int4v;

#define CHUNK 1024
#define NBINS 32
#define NCLS  10
#define NREP  8

__global__ __launch_bounds__(256) void dvh_main(
    const float* __restrict__ pred, const float* __restrict__ targ,
    const float* __restrict__ mask, float* __restrict__ gD, float* __restrict__ gN,
    int nblocks)
{
    __shared__ float2 sE[CHUNK];                 // (Ep,Et) per voxel, 8 KB
    __shared__ unsigned short mT[NCLS * CHUNK];  // bf16 masks [10][1024] swizzled, 20 KB

    const int tid  = threadIdx.x;
    const int lane = tid & 63;
    const int w    = tid >> 6;       // wave 0..3
    const int n15  = lane & 15;      // MFMA row/col index
    const int g    = lane >> 4;      // k-group 0..3

    const size_t vbaseA = (size_t)blockIdx.x * CHUNK;              // n=0 half
    const size_t vbaseB = (size_t)(blockIdx.x + nblocks) * CHUNK;  // n=1 half

    const float K1 = __expf((float)n15);        // e^bin, bins 0..15
    const float K2 = K1 * 8886110.5f;           // * e^16 -> bins 16..31

    // precompute staging (v,c) start once (shared by both chunks)
    const int f0  = tid * 4;
    const int vv0 = f0 / 10;
    const int cc0 = f0 - vv0 * 10;

    // ---- chunk A: load ----
    float4 pA = ((const float4*)(pred + vbaseA))[tid];
    float4 tA = ((const float4*)(targ + vbaseA))[tid];
    uint4 mvA[10];
    {
        const uint4* m4g = (const uint4*)(mask + vbaseA * NCLS);
        #pragma unroll
        for (int k = 0; k < 10; ++k) mvA[k] = m4g[k * 256 + tid];
    }

    // ---- stage A ----
    *(float4*)&sE[4 * tid]     = make_float4(__expf(-32.f * pA.x), __expf(-32.f * tA.x),
                                             __expf(-32.f * pA.y), __expf(-32.f * tA.y));
    *(float4*)&sE[4 * tid + 2] = make_float4(__expf(-32.f * pA.z), __expf(-32.f * tA.z),
                                             __expf(-32.f * pA.w), __expf(-32.f * tA.w));
    {
        int vv = vv0, cc = cc0;
        #pragma unroll
        for (int k = 0; k < 10; ++k) {
            unsigned int e[4] = {mvA[k].x, mvA[k].y, mvA[k].z, mvA[k].w};
            #pragma unroll
            for (int q = 0; q < 4; ++q) {
                mT[cc * CHUNK + (((vv >> 3) ^ (cc & 7)) << 3) + (vv & 7)] =
                    (unsigned short)(e[q] >> 16);
                cc += 1;
                int wrap = (cc >= 10);
                cc -= wrap * 10;
                vv += wrap;
            }
            vv += 102;   // k-stride 1024 floats = 102*10 + 4
        }
    }
    __syncthreads();

    // ---- issue chunk B loads now; latency hides under compute A ----
    float4 pB = ((const float4*)(pred + vbaseB))[tid];
    float4 tB = ((const float4*)(targ + vbaseB))[tid];
    uint4 mvB[10];
    {
        const uint4* m4g = (const uint4*)(mask + vbaseB * NCLS);
        #pragma unroll
        for (int k = 0; k < 10; ++k) mvB[k] = m4g[k * 256 + tid];
    }

    f32x4 acc1 = {0,0,0,0};          // bins 0-15  (summed over both chunks)
    f32x4 acc2 = {0,0,0,0};          // bins 16-31
    f32x4 cntA = {0,0,0,0};          // n0 voxel counts
    f32x4 cntB = {0,0,0,0};          // n1 voxel counts
    short8 ones;
    #pragma unroll
    for (int i = 0; i < 8; ++i) ones[i] = (short)0x3F80;   // bf16 1.0

    // B-row: lanes n15>=10 read row n15-10 (junk-but-valid; MFMA output
    // columns 10..15 are never consumed).
    const int brow = (n15 < NCLS) ? n15 : (n15 - NCLS);

    // ================= compute A =================
    #pragma unroll
    for (int st = 0; st < 8; ++st) {
        const int vb = (w * 8 + st) * 32;
        const int v0 = vb + g * 8;
        short8 fb = *(const short8*)&mT[brow * CHUNK + (((v0 >> 3) ^ (brow & 7)) << 3)];
        const float4* e4 = (const float4*)&sE[v0];
        int u1[4], u2[4];
        #pragma unroll
        for (int j = 0; j < 4; ++j) {
            float4 q = e4[j];
            float dea = q.y - q.x, deb = q.w - q.z;
            float pa = fmaf(q.x, K1, 1.f) * fmaf(q.y, K1, 1.f);
            float pb = fmaf(q.z, K1, 1.f) * fmaf(q.w, K1, 1.f);
            float sa = dea * K1 * __builtin_amdgcn_rcpf(pa);
            float sb = deb * K1 * __builtin_amdgcn_rcpf(pb);
            unsigned h1;
            asm("v_cvt_pk_bf16_f32 %0, %1, %2" : "=v"(h1) : "v"(sa), "v"(sb));
            u1[j] = (int)h1;
            float pc = fmaf(q.x, K2, 1.f) * fmaf(q.y, K2, 1.f);
            float pd = fmaf(q.z, K2, 1.f) * fmaf(q.w, K2, 1.f);
            float sc = dea * K2 * __builtin_amdgcn_rcpf(pc);
            float sd = deb * K2 * __builtin_amdgcn_rcpf(pd);
            unsigned h2;
            asm("v_cvt_pk_bf16_f32 %0, %1, %2" : "=v"(h2) : "v"(sc), "v"(sd));
            u2[j] = (int)h2;
        }
        int4v t1 = {u1[0], u1[1], u1[2], u1[3]};
        int4v t2 = {u2[0], u2[1], u2[2], u2[3]};
        short8 A1 = __builtin_bit_cast(short8, t1);
        short8 A2 = __builtin_bit_cast(short8, t2);
        acc1 = __builtin_amdgcn_mfma_f32_16x16x32_bf16(A1, fb, acc1, 0, 0, 0);
        acc2 = __builtin_amdgcn_mfma_f32_16x16x32_bf16(A2, fb, acc2, 0, 0, 0);
        cntA = __builtin_amdgcn_mfma_f32_16x16x32_bf16(ones, fb, cntA, 0, 0, 0);
    }
    __syncthreads();                 // all waves done reading A's LDS

    // ---- stage B ----
    *(float4*)&sE[4 * tid]     = make_float4(__expf(-32.f * pB.x), __expf(-32.f * tB.x),
                                             __expf(-32.f * pB.y), __expf(-32.f * tB.y));
    *(float4*)&sE[4 * tid + 2] = make_float4(__expf(-32.f * pB.z), __expf(-32.f * tB.z),
                                             __expf(-32.f * pB.w), __expf(-32.f * tB.w));
    {
        int vv = vv0, cc = cc0;
        #pragma unroll
        for (int k = 0; k < 10; ++k) {
            unsigned int e[4] = {mvB[k].x, mvB[k].y, mvB[k].z, mvB[k].w};
            #pragma unroll
            for (int q = 0; q < 4; ++q) {
                mT[cc * CHUNK + (((vv >> 3) ^ (cc & 7)) << 3) + (vv & 7)] =
                    (unsigned short)(e[q] >> 16);
                cc += 1;
                int wrap = (cc >= 10);
                cc -= wrap * 10;
                vv += wrap;
            }
            vv += 102;
        }
    }
    __syncthreads();

    // ================= compute B =================
    #pragma unroll
    for (int st = 0; st < 8; ++st) {
        const int vb = (w * 8 + st) * 32;
        const int v0 = vb + g * 8;
        short8 fb = *(const short8*)&mT[brow * CHUNK + (((v0 >> 3) ^ (brow & 7)) << 3)];
        const float4* e4 = (const float4*)&sE[v0];
        int u1[4], u2[4];
        #pragma unroll
        for (int j = 0; j < 4; ++j) {
            float4 q = e4[j];
            float dea = q.y - q.x, deb = q.w - q.z;
            float pa = fmaf(q.x, K1, 1.f) * fmaf(q.y, K1, 1.f);
            float pb = fmaf(q.z, K1, 1.f) * fmaf(q.w, K1, 1.f);
            float sa = dea * K1 * __builtin_amdgcn_rcpf(pa);
            float sb = deb * K1 * __builtin_amdgcn_rcpf(pb);
            unsigned h1;
            asm("v_cvt_pk_bf16_f32 %0, %1, %2" : "=v"(h1) : "v"(sa), "v"(sb));
            u1[j] = (int)h1;
            float pc = fmaf(q.x, K2, 1.f) * fmaf(q.y, K2, 1.f);
            float pd = fmaf(q.z, K2, 1.f) * fmaf(q.w, K2, 1.f);
            float sc = dea * K2 * __builtin_amdgcn_rcpf(pc);
            float sd = deb * K2 * __builtin_amdgcn_rcpf(pd);
            unsigned h2;
            asm("v_cvt_pk_bf16_f32 %0, %1, %2" : "=v"(h2) : "v"(sc), "v"(sd));
            u2[j] = (int)h2;
        }
        int4v t1 = {u1[0], u1[1], u1[2], u1[3]};
        int4v t2 = {u2[0], u2[1], u2[2], u2[3]};
        short8 A1 = __builtin_bit_cast(short8, t1);
        short8 A2 = __builtin_bit_cast(short8, t2);
        acc1 = __builtin_amdgcn_mfma_f32_16x16x32_bf16(A1, fb, acc1, 0, 0, 0);
        acc2 = __builtin_amdgcn_mfma_f32_16x16x32_bf16(A2, fb, acc2, 0, 0, 0);
        cntB = __builtin_amdgcn_mfma_f32_16x16x32_bf16(ones, fb, cntB, 0, 0, 0);
    }
    __syncthreads();                 // all waves done reading mT

    // ---- epilogue: block reduce via LDS (reuse mT), then replicated atomics ----
    float* red   = (float*)mT;       // [4 waves][32 bins][10 cls] = 1280 floats
    float* redNA = red + 1280;       // [4 waves][10] n0 counts
    float* redNB = red + 1320;       // [4 waves][10] n1 counts

    if (n15 < NCLS) {
        #pragma unroll
        for (int r = 0; r < 4; ++r) {
            int b1 = g * 4 + r;                  // C/D: row=(lane>>4)*4+reg, col=lane&15
            red[(w * 32 + b1) * NCLS + n15]      = acc1[r];
            red[(w * 32 + 16 + b1) * NCLS + n15] = acc2[r];
        }
    }
    if (lane < NCLS) {
        redNA[w * NCLS + lane] = cntA[0];
        redNB[w * NCLS + lane] = cntB[0];
    }
    __syncthreads();

    const int rep = blockIdx.x & (NREP - 1);
    float* gDr = gD + rep * (NBINS * NCLS);
    float* gNr = gN + rep * (2 * NCLS);

    for (int i = tid; i < NBINS * NCLS; i += 256) {
        float s = red[i] + red[320 + i] + red[640 + i] + red[960 + i];
        atomicAdd(&gDr[i], s);
    }
    if (tid < 2 * NCLS) {
        float* rn = (tid < NCLS) ? redNA : redNB;
        int c = (tid < NCLS) ? tid : (tid - NCLS);
        float s = rn[c] + rn[10 + c] + rn[20 + c] + rn[30 + c];
        atomicAdd(&gNr[tid], s);
    }
}

__global__ __launch_bounds__(512) void dvh_final(
    const float* __restrict__ gD, const float* __restrict__ gN, float* __restrict__ out)
{
    __shared__ float red[512];
    __shared__ float nvs[2 * NCLS];
    const int t = threadIdx.x;

    if (t < 2 * NCLS) {
        float s = 1.f;
        #pragma unroll
        for (int r = 0; r < NREP; ++r) s += gN[r * (2 * NCLS) + t];
        nvs[t] = s;
    }
    float d = 0.f;
    if (t < NBINS * NCLS) {
        #pragma unroll
        for (int r = 0; r < NREP; ++r) d += gD[r * (NBINS * NCLS) + t];
    }
    __syncthreads();

    float v = 0.f;
    if (t < NBINS * NCLS) {
        int c = t % NCLS;
        float nv0 = nvs[c], nv1 = nvs[NCLS + c];
        v = d * d * (1.f / (nv0 * nv0) + 1.f / (nv1 * nv1));
    }
    red[t] = v;
    __syncthreads();
    for (int s = 256; s > 0; s >>= 1) {
        if (t < s) red[t] += red[t + s];
        __syncthreads();
    }
    if (t == 0) out[0] = red[0] * (1.f / 1280.f);
}

extern "C" void kernel_launch(void* const* d_in, const int* in_sizes, int n_in,
                              void* d_out, int out_size, void* d_ws, size_t ws_size,
                              hipStream_t stream) {
    const float* pred = (const float*)d_in[0];
    const float* targ = (const float*)d_in[1];
    const float* mask = (const float*)d_in[2];
    float* gD = (float*)d_ws;                                    // NREP x 320 floats
    float* gN = (float*)((char*)d_ws + NREP * NBINS * NCLS * 4); // NREP x 20 floats

    hipMemsetAsync(d_ws, 0, NREP * (NBINS * NCLS + 2 * NCLS) * 4, stream);

    int totalVox = in_sizes[0];              // N*V = 4194304
    int nblocks  = totalVox / CHUNK / 2;     // 2048 blocks, 2 chunks each

    dvh_main<<<nblocks, 256, 0, stream>>>(pred, targ, mask, gD, gN, nblocks);
    dvh_final<<<1, 512, 0, stream>>>(gD, gN, (float*)d_out);
}

// Round 20
// 50.056 us; speedup vs baseline: 3.3212x; 1.0243x over previous
//
#include <hip/hip_runtime.h>

typedef __attribute__((ext_vector_type(8))) short short8;   // 8 bf16 (4 VGPR)
typedef __attribute__((ext_vector_type(4))) float f32x4;    // MFMA C/D
typedef __attribute__((ext_vector_type(4))) int int4v;

#define CHUNK 1024
#define NBINS 32
#define NCLS  10
#define NREP  8

__global__ __launch_bounds__(256) void dvh_main(
    const float* __restrict__ pred, const float* __restrict__ targ,
    const float* __restrict__ mask, float* __restrict__ gD, float* __restrict__ gN,
    int chunksPerN)
{
    __shared__ float2 sE[CHUNK];                 // (Ep,Et) per voxel, 8 KB
    __shared__ unsigned short mT[NCLS * CHUNK];  // bf16 masks [10][1024] swizzled, 20 KB
    // total 28 KB -> 5 blocks/CU

    const int tid  = threadIdx.x;
    const int lane = tid & 63;
    const int w    = tid >> 6;       // wave 0..3
    const int n15  = lane & 15;      // MFMA row/col index
    const int g    = lane >> 4;      // k-group 0..3

    const int chunk = blockIdx.x;
    const size_t vbase = (size_t)chunk * CHUNK;

    // ---- issue ALL global loads first (latency overlaps across blocks) ----
    float4 p = ((const float4*)(pred + vbase))[tid];     // voxels 4t..4t+3
    float4 t = ((const float4*)(targ + vbase))[tid];
    uint4 mv[10];
    {
        const uint4* m4g = (const uint4*)(mask + vbase * NCLS);
        #pragma unroll
        for (int k = 0; k < 10; ++k) mv[k] = m4g[k * 256 + tid];
    }

    const float K1 = __expf((float)n15);        // e^bin, bins 0..15
    const float K2 = K1 * 8886110.5f;           // * e^16 -> bins 16..31

    // ---- stage doses: exp once per voxel ----
    *(float4*)&sE[4 * tid]     = make_float4(__expf(-32.f * p.x), __expf(-32.f * t.x),
                                             __expf(-32.f * p.y), __expf(-32.f * t.y));
    *(float4*)&sE[4 * tid + 2] = make_float4(__expf(-32.f * p.z), __expf(-32.f * t.z),
                                             __expf(-32.f * p.w), __expf(-32.f * t.w));
    // ---- stage masks: 0/1 f32 -> bf16 (top 16 bits), swizzled transpose ----
    {
        int f0 = tid * 4;
        int vv = f0 / 10;
        int cc = f0 - vv * 10;
        #pragma unroll
        for (int k = 0; k < 10; ++k) {
            unsigned int e[4] = {mv[k].x, mv[k].y, mv[k].z, mv[k].w};
            #pragma unroll
            for (int q = 0; q < 4; ++q) {
                mT[cc * CHUNK + (((vv >> 3) ^ (cc & 7)) << 3) + (vv & 7)] =
                    (unsigned short)(e[q] >> 16);
                cc += 1;
                int wrap = (cc >= 10);
                cc -= wrap * 10;
                vv += wrap;
            }
            vv += 102;   // k-stride 1024 floats = 102*10 + 4
        }
    }
    __syncthreads();

    f32x4 acc1 = {0,0,0,0};          // bins 0-15
    f32x4 acc2 = {0,0,0,0};          // bins 16-31
    f32x4 cnt  = {0,0,0,0};          // voxel counts
    short8 ones;
    #pragma unroll
    for (int i = 0; i < 8; ++i) ones[i] = (short)0x3F80;   // bf16 1.0

    // B-row: lanes n15>=10 have no class; read row n15-10 (junk-but-valid,
    // feeds only MFMA output columns 10..15, which are never consumed).
    const int brow = (n15 < NCLS) ? n15 : (n15 - NCLS);

    #pragma unroll
    for (int st = 0; st < 8; ++st) {
        const int vb = (w * 8 + st) * 32;    // this wave's 32-voxel K-block
        const int v0 = vb + g * 8;           // this lane's 8 voxels
        short8 fb = *(const short8*)&mT[brow * CHUNK + (((v0 >> 3) ^ (brow & 7)) << 3)];
        const float4* e4 = (const float4*)&sE[v0];

        int u1[4], u2[4];
        #pragma unroll
        for (int j = 0; j < 4; ++j) {
            float4 q = e4[j];                 // vox a: (q.x,q.y)  vox b: (q.z,q.w)
            float dea = q.y - q.x, deb = q.w - q.z;
            float pa = fmaf(q.x, K1, 1.f) * fmaf(q.y, K1, 1.f);
            float pb = fmaf(q.z, K1, 1.f) * fmaf(q.w, K1, 1.f);
            float sa = dea * K1 * __builtin_amdgcn_rcpf(pa);
            float sb = deb * K1 * __builtin_amdgcn_rcpf(pb);
            unsigned h1;
            asm("v_cvt_pk_bf16_f32 %0, %1, %2" : "=v"(h1) : "v"(sa), "v"(sb));
            u1[j] = (int)h1;
            float pc = fmaf(q.x, K2, 1.f) * fmaf(q.y, K2, 1.f);
            float pd = fmaf(q.z, K2, 1.f) * fmaf(q.w, K2, 1.f);
            float sc = dea * K2 * __builtin_amdgcn_rcpf(pc);
            float sd = deb * K2 * __builtin_amdgcn_rcpf(pd);
            unsigned h2;
            asm("v_cvt_pk_bf16_f32 %0, %1, %2" : "=v"(h2) : "v"(sc), "v"(sd));
            u2[j] = (int)h2;
        }
        int4v t1 = {u1[0], u1[1], u1[2], u1[3]};
        int4v t2 = {u2[0], u2[1], u2[2], u2[3]};
        short8 A1 = __builtin_bit_cast(short8, t1);
        short8 A2 = __builtin_bit_cast(short8, t2);

        acc1 = __builtin_amdgcn_mfma_f32_16x16x32_bf16(A1, fb, acc1, 0, 0, 0);
        acc2 = __builtin_amdgcn_mfma_f32_16x16x32_bf16(A2, fb, acc2, 0, 0, 0);
        cnt  = __builtin_amdgcn_mfma_f32_16x16x32_bf16(ones, fb, cnt, 0, 0, 0);
    }
    __syncthreads();                  // all waves done reading mT

    // ---- epilogue: block reduce via LDS (reuse mT), then replicated atomics ----
    float* red  = (float*)mT;        // [4 waves][32 bins][10 cls] = 1280 floats
    float* redN = red + 1280;        // [4 waves][10]

    if (n15 < NCLS) {
        #pragma unroll
        for (int r = 0; r < 4; ++r) {
            int b1 = g * 4 + r;                  // C/D: row=(lane>>4)*4+reg, col=lane&15
            red[(w * 32 + b1) * NCLS + n15]      = acc1[r];
            red[(w * 32 + 16 + b1) * NCLS + n15] = acc2[r];
        }
    }
    if (lane < NCLS) redN[w * NCLS + lane] = cnt[0];   // row 0 of count tile
    __syncthreads();

    const int rep = chunk & (NREP - 1);
    float* gDr = gD + rep * (NBINS * NCLS);
    float* gNr = gN + rep * (2 * NCLS);
    const int nsel = (chunk < chunksPerN) ? 0 : 1;

    for (int i = tid; i < NBINS * NCLS; i += 256) {
        float s = red[i] + red[320 + i] + red[640 + i] + red[960 + i];
        atomicAdd(&gDr[i], s);
    }
    if (tid < NCLS) {
        float s = redN[tid] + redN[10 + tid] + redN[20 + tid] + redN[30 + tid];
        atomicAdd(&gNr[nsel * NCLS + tid], s);
    }
}

__global__ __launch_bounds__(512) void dvh_final(
    const float* __restrict__ gD, const float* __restrict__ gN, float* __restrict__ out)
{
    __shared__ float red[512];
    __shared__ float nvs[2 * NCLS];
    const int t = threadIdx.x;

    if (t < 2 * NCLS) {
        float s = 1.f;
        #pragma unroll
        for (int r = 0; r < NREP; ++r) s += gN[r * (2 * NCLS) + t];
        nvs[t] = s;
    }
    float d = 0.f;
    if (t < NBINS * NCLS) {
        #pragma unroll
        for (int r = 0; r < NREP; ++r) d += gD[r * (NBINS * NCLS) + t];
    }
    __syncthreads();

    float v = 0.f;
    if (t < NBINS * NCLS) {
        int c = t % NCLS;
        float nv0 = nvs[c], nv1 = nvs[NCLS + c];
        v = d * d * (1.f / (nv0 * nv0) + 1.f / (nv1 * nv1));
    }
    red[t] = v;
    __syncthreads();
    for (int s = 256; s > 0; s >>= 1) {
        if (t < s) red[t] += red[t + s];
        __syncthreads();
    }
    if (t == 0) out[0] = red[0] * (1.f / 1280.f);
}

extern "C" void kernel_launch(void* const* d_in, const int* in_sizes, int n_in,
                              void* d_out, int out_size, void* d_ws, size_t ws_size,
                              hipStream_t stream) {
    const float* pred = (const float*)d_in[0];
    const float* targ = (const float*)d_in[1];
    const float* mask = (const float*)d_in[2];
    float* gD = (float*)d_ws;                                    // NREP x 320 floats
    float* gN = (float*)((char*)d_ws + NREP * NBINS * NCLS * 4); // NREP x 20 floats

    hipMemsetAsync(d_ws, 0, NREP * (NBINS * NCLS + 2 * NCLS) * 4, stream);

    int totalVox    = in_sizes[0];           // N*V = 4194304
    int chunksTotal = totalVox / CHUNK;      // 4096
    int chunksPerN  = chunksTotal / 2;       // 2048

    dvh_main<<<chunksTotal, 256, 0, stream>>>(pred, targ, mask, gD, gN, chunksPerN);
    dvh_final<<<1, 512, 0, stream>>>(gD, gN, (float*)d_out);
}